// Round 1
// baseline (140.392 us; speedup 1.0000x reference)
//
#include <hip/hip_runtime.h>

// RegistrationRecall: out = (sqrt(mean_n(min_m ||src_n - tgt_m||)^2) < 0.1) ? 1 : 0
// N = M = 8192, D = 3, fp32.

#define N_SRC 8192
#define N_TGT 8192
#define TPS   16                       // threads cooperating per source point
#define BLOCK 256
#define SRC_PER_BLOCK (BLOCK / TPS)    // 16 sources per block
#define NBLOCKS (N_SRC / SRC_PER_BLOCK) // 512 blocks

__global__ __launch_bounds__(BLOCK) void knn_partial(const float* __restrict__ src,
                                                     const float* __restrict__ tgt,
                                                     float* __restrict__ partials) {
    const int tid = threadIdx.x;
    const int sub = tid & (TPS - 1);          // which slice of targets
    const int s   = blockIdx.x * SRC_PER_BLOCK + (tid >> 4);

    const float sx = src[3 * s + 0];
    const float sy = src[3 * s + 1];
    const float sz = src[3 * s + 2];

    float minsq = 1e30f;
    // lanes 0..15 read targets j..j+15 (contiguous 192B); groups broadcast.
    #pragma unroll 4
    for (int j = sub; j < N_TGT; j += TPS) {
        const float tx = tgt[3 * j + 0];
        const float ty = tgt[3 * j + 1];
        const float tz = tgt[3 * j + 2];
        const float dx = sx - tx;
        const float dy = sy - ty;
        const float dz = sz - tz;
        const float d2 = dx * dx + dy * dy + dz * dz;
        minsq = fminf(minsq, d2);
    }

    // butterfly min across the 16 sub-lanes (lane groups are low-4-bit cosets)
    #pragma unroll
    for (int off = 1; off < TPS; off <<= 1)
        minsq = fminf(minsq, __shfl_xor(minsq, off));

    // replicate reference rounding: d = sqrt(minsq); contribute d*d
    const float d = sqrtf(minsq);
    float contrib = (sub == 0) ? d * d : 0.0f;

    // sum the 4 group-leaders of this 64-lane wave (other lanes hold 0)
    contrib += __shfl_xor(contrib, 16);
    contrib += __shfl_xor(contrib, 32);

    __shared__ float wsum[BLOCK / 64];
    if ((tid & 63) == 0) wsum[tid >> 6] = contrib;
    __syncthreads();
    if (tid == 0) {
        float t = 0.0f;
        #pragma unroll
        for (int w = 0; w < BLOCK / 64; ++w) t += wsum[w];
        partials[blockIdx.x] = t;   // all NBLOCKS slots overwritten each launch
    }
}

__global__ __launch_bounds__(256) void knn_finalize(const float* __restrict__ partials,
                                                    float* __restrict__ out) {
    const int tid = threadIdx.x;
    float v = partials[tid] + partials[tid + 256];   // NBLOCKS = 512 partials

    #pragma unroll
    for (int off = 1; off < 64; off <<= 1)
        v += __shfl_xor(v, off);

    __shared__ float wsum[4];
    if ((tid & 63) == 0) wsum[tid >> 6] = v;
    __syncthreads();
    if (tid == 0) {
        const float total = wsum[0] + wsum[1] + wsum[2] + wsum[3];
        const float rmse = sqrtf(total / (float)N_SRC);
        out[0] = (rmse < 0.1f) ? 1.0f : 0.0f;
    }
}

extern "C" void kernel_launch(void* const* d_in, const int* in_sizes, int n_in,
                              void* d_out, int out_size, void* d_ws, size_t ws_size,
                              hipStream_t stream) {
    const float* src = (const float*)d_in[0];
    const float* tgt = (const float*)d_in[1];
    float* partials  = (float*)d_ws;     // NBLOCKS floats
    float* out       = (float*)d_out;

    knn_partial<<<NBLOCKS, BLOCK, 0, stream>>>(src, tgt, partials);
    knn_finalize<<<1, 256, 0, stream>>>(partials, out);
}

// Round 2
// 68.002 us; speedup vs baseline: 2.0645x; 2.0645x over previous
//
#include <hip/hip_runtime.h>

// RegistrationRecall: out = (sqrt(mean_n(min_m ||src_n - tgt_m||)^2) < 0.1) ? 1 : 0
// N = M = 8192, D = 3, fp32.
//
// Structure: each 64-lane wave owns S=4 source points (registers); lanes split
// the 8192 targets. Each lane loads 4 consecutive targets via 3 float4 loads
// (48 contiguous bytes), computes 16 pairs per load-group -> ~224 VALU cycles
// per 3 loads, hiding L2 latency with ILP instead of occupancy.

#define N_SRC 8192
#define N_TGT 8192
#define S     4                         // sources per wave
#define BLOCK 256                       // 4 waves per block
#define GROUPS (N_SRC / S)              // 2048 wave-groups
#define NBLOCKS (GROUPS / 4)            // 512 blocks
#define TGT_PER_LANE_ITER 4
#define ITERS (N_TGT / (64 * TGT_PER_LANE_ITER))   // 32

__global__ __launch_bounds__(BLOCK) void knn_partial(const float* __restrict__ src,
                                                     const float* __restrict__ tgt,
                                                     float* __restrict__ partials) {
    const int tid  = threadIdx.x;
    const int lane = tid & 63;
    const int wave = tid >> 6;
    const int g    = blockIdx.x * 4 + wave;        // source group id

    // load the wave's 4 sources (same for all lanes)
    float sx[S], sy[S], sz[S];
    const float* sp = src + g * S * 3;
    #pragma unroll
    for (int i = 0; i < S; ++i) {
        sx[i] = sp[3 * i + 0];
        sy[i] = sp[3 * i + 1];
        sz[i] = sp[3 * i + 2];
    }

    float m[S];
    #pragma unroll
    for (int i = 0; i < S; ++i) m[i] = 1e30f;

    // lane l handles targets [l*4 + it*256, ...): 3 float4 loads = 4 targets
    const float* tb = tgt + lane * (TGT_PER_LANE_ITER * 3);

    #pragma unroll 2
    for (int it = 0; it < ITERS; ++it) {
        const float4 t0 = *(const float4*)(tb + 0);
        const float4 t1 = *(const float4*)(tb + 4);
        const float4 t2 = *(const float4*)(tb + 8);
        tb += 64 * TGT_PER_LANE_ITER * 3;

        const float tx[4] = {t0.x, t0.w, t1.z, t2.y};
        const float ty[4] = {t0.y, t1.x, t1.w, t2.z};
        const float tz[4] = {t0.z, t1.y, t2.x, t2.w};

        #pragma unroll
        for (int j = 0; j < 4; ++j) {
            #pragma unroll
            for (int i = 0; i < S; ++i) {
                const float dx = sx[i] - tx[j];
                const float dy = sy[i] - ty[j];
                const float dz = sz[i] - tz[j];
                const float d2 = dx * dx + dy * dy + dz * dz;
                m[i] = fminf(m[i], d2);
            }
        }
    }

    // butterfly min across the 64 lanes for each of the 4 sources
    #pragma unroll
    for (int off = 1; off < 64; off <<= 1) {
        #pragma unroll
        for (int i = 0; i < S; ++i)
            m[i] = fminf(m[i], __shfl_xor(m[i], off));
    }

    // replicate reference rounding: d = sqrt(min d2); accumulate d*d
    float c = 0.0f;
    #pragma unroll
    for (int i = 0; i < S; ++i) {
        const float d = sqrtf(m[i]);
        c += d * d;
    }

    __shared__ float wsum[BLOCK / 64];
    if (lane == 0) wsum[wave] = c;
    __syncthreads();
    if (tid == 0)
        partials[blockIdx.x] = wsum[0] + wsum[1] + wsum[2] + wsum[3];
}

__global__ __launch_bounds__(256) void knn_finalize(const float* __restrict__ partials,
                                                    float* __restrict__ out) {
    const int tid = threadIdx.x;
    float v = partials[tid] + partials[tid + 256];   // NBLOCKS = 512 partials

    #pragma unroll
    for (int off = 1; off < 64; off <<= 1)
        v += __shfl_xor(v, off);

    __shared__ float wsum[4];
    if ((tid & 63) == 0) wsum[tid >> 6] = v;
    __syncthreads();
    if (tid == 0) {
        const float total = wsum[0] + wsum[1] + wsum[2] + wsum[3];
        const float rmse = sqrtf(total / (float)N_SRC);
        out[0] = (rmse < 0.1f) ? 1.0f : 0.0f;
    }
}

extern "C" void kernel_launch(void* const* d_in, const int* in_sizes, int n_in,
                              void* d_out, int out_size, void* d_ws, size_t ws_size,
                              hipStream_t stream) {
    const float* src = (const float*)d_in[0];
    const float* tgt = (const float*)d_in[1];
    float* partials  = (float*)d_ws;     // NBLOCKS floats
    float* out       = (float*)d_out;

    knn_partial<<<NBLOCKS, BLOCK, 0, stream>>>(src, tgt, partials);
    knn_finalize<<<1, 256, 0, stream>>>(partials, out);
}